// Round 4
// baseline (1279.546 us; speedup 1.0000x reference)
//
#include <hip/hip_runtime.h>

#define BB 256
#define LL 1024
#define TT 128
#define NTH 256   // 4 waves

// LDS-only barrier: does NOT drain vmcnt, so in-flight global prefetch loads
// stay outstanding across the barrier (__syncthreads drains vmcnt(0) too).
__device__ __forceinline__ void lds_barrier() {
    asm volatile("s_waitcnt lgkmcnt(0)\n\ts_barrier" ::);
}

struct SmallSmem {
    float state[TT];          // current Viterbi state (float4-aligned, first)
    float pv[4 * TT];         // pv[w*128 + j]: per-wave partial best value
    int   pi[4 * TT];         // pi[w*128 + j]: per-wave partial best GLOBAL index
    unsigned char tags[LL];   // decoded tags staging
};

__global__ __launch_bounds__(NTH)
void viterbi_kernel(const float* __restrict__ x,
                    const int* __restrict__ lengths,
                    const float* __restrict__ trans,
                    int* __restrict__ out) {
    __shared__ SmallSmem sm;
    extern __shared__ unsigned char bp[];   // LL*TT bytes, backpointers in LDS

    const int b    = blockIdx.x;
    const int tid  = threadIdx.x;
    const int lane = tid & 63;
    const int w    = tid >> 6;      // wave 0..3 owns preds [32w, 32w+32)
    const int j1   = lane;          // tag column A
    const int j2   = lane + 64;     // tag column B

    int lenb = lengths[b];
    if (lenb < 1) lenb = 1;
    if (lenb > LL) lenb = LL;

    // Register-cache trans for this thread's 32 preds x 2 columns:
    // ta[ii] = trans[32w+ii][j1], tb[ii] = trans[32w+ii][j2]
    float ta[32], tb[32];
    #pragma unroll
    for (int ii = 0; ii < 32; ++ii) {
        ta[ii] = trans[(w * 32 + ii) * TT + j1];
        tb[ii] = trans[(w * 32 + ii) * TT + j2];
    }

    const float* xb = x + (size_t)b * LL * TT;

    if (tid < TT) sm.state[tid] = xb[tid];

    // Emission prefetch for phase-2 owners (tid<128 own j=tid).
    float xv_cur = 0.0f, xv_next = 0.0f;
    if (tid < TT && lenb > 1) xv_cur = xb[TT + tid];
    lds_barrier();

    // ---------------- forward ----------------
    for (int t = 1; t < lenb; ++t) {
        if (tid < TT) {
            int tn = (t + 1 < lenb) ? (t + 1) : (lenb - 1);
            xv_next = xb[tn * TT + tid];   // floats across lds_barrier (vmcnt)
        }

        // Phase 1: each wave scans its 32 preds for both of its j columns.
        // Residue accumulator r tracks local ii = 4k+r, k ascending; strict >
        // keeps the LOWEST index within each residue (jnp.argmax = first max).
        float a0 = -3.4e38f, a1 = -3.4e38f, a2 = -3.4e38f, a3 = -3.4e38f;
        float b0 = -3.4e38f, b1 = -3.4e38f, b2 = -3.4e38f, b3 = -3.4e38f;
        int   ai0 = 0, ai1 = 1, ai2 = 2, ai3 = 3;
        int   bi0 = 0, bi1 = 1, bi2 = 2, bi3 = 3;
        const float4* st4 = reinterpret_cast<const float4*>(sm.state + w * 32);
        #pragma unroll
        for (int k = 0; k < 8; ++k) {
            float4 sv = st4[k];            // wave-uniform broadcast ds_read_b128
            float sA0 = sv.x + ta[4 * k + 0], sB0 = sv.x + tb[4 * k + 0];
            float sA1 = sv.y + ta[4 * k + 1], sB1 = sv.y + tb[4 * k + 1];
            float sA2 = sv.z + ta[4 * k + 2], sB2 = sv.z + tb[4 * k + 2];
            float sA3 = sv.w + ta[4 * k + 3], sB3 = sv.w + tb[4 * k + 3];
            if (sA0 > a0) { a0 = sA0; ai0 = 4 * k + 0; }
            if (sA1 > a1) { a1 = sA1; ai1 = 4 * k + 1; }
            if (sA2 > a2) { a2 = sA2; ai2 = 4 * k + 2; }
            if (sA3 > a3) { a3 = sA3; ai3 = 4 * k + 3; }
            if (sB0 > b0) { b0 = sB0; bi0 = 4 * k + 0; }
            if (sB1 > b1) { b1 = sB1; bi1 = 4 * k + 1; }
            if (sB2 > b2) { b2 = sB2; bi2 = 4 * k + 2; }
            if (sB3 > b3) { b3 = sB3; bi3 = 4 * k + 3; }
        }
        // Merge residues with EXACT first-index tie-break (local ii order).
        float av = a0; int ax = ai0;
        if (a1 > av || (a1 == av && ai1 < ax)) { av = a1; ax = ai1; }
        if (a2 > av || (a2 == av && ai2 < ax)) { av = a2; ax = ai2; }
        if (a3 > av || (a3 == av && ai3 < ax)) { av = a3; ax = ai3; }
        float bv = b0; int bx = bi0;
        if (b1 > bv || (b1 == bv && bi1 < bx)) { bv = b1; bx = bi1; }
        if (b2 > bv || (b2 == bv && bi2 < bx)) { bv = b2; bx = bi2; }
        if (b3 > bv || (b3 == bv && bi3 < bx)) { bv = b3; bx = bi3; }
        sm.pv[w * TT + j1] = av;  sm.pi[w * TT + j1] = ax + w * 32;
        sm.pv[w * TT + j2] = bv;  sm.pi[w * TT + j2] = bx + w * 32;
        lds_barrier();

        // Phase 2: threads 0..127 merge the 4 wave-partials for j = tid.
        // Wave partials in ascending pred order; all w0 indices < w1 < w2 < w3,
        // so strict > (earlier wave wins ties) = first-index semantics.
        if (tid < TT) {
            float mv = sm.pv[tid];            int mx = sm.pi[tid];
            float v1 = sm.pv[TT + tid];       int i1 = sm.pi[TT + tid];
            float v2 = sm.pv[2 * TT + tid];   int i2 = sm.pi[2 * TT + tid];
            float v3 = sm.pv[3 * TT + tid];   int i3 = sm.pi[3 * TT + tid];
            if (v1 > mv) { mv = v1; mx = i1; }
            if (v2 > mv) { mv = v2; mx = i2; }
            if (v3 > mv) { mv = v3; mx = i3; }
            sm.state[tid] = mv + xv_cur;
            bp[t * TT + tid] = (unsigned char)mx;
            xv_cur = xv_next;
        }
        lds_barrier();
    }

    // ---------------- backward ----------------
    if (tid == 0) {
        // last_tag = argmax(state), first-index tiebreak (sequential strict >)
        float bv = sm.state[0]; int ix = 0;
        for (int i = 1; i < TT; ++i) {
            float v = sm.state[i];
            if (v > bv) { bv = v; ix = i; }
        }
        int carry = ix;
        for (int t = lenb - 1; t >= 1; --t) {
            sm.tags[t] = (unsigned char)carry;
            carry = bp[t * TT + carry];
        }
        sm.tags[0] = (unsigned char)carry;
    }
    lds_barrier();

    int* outb = out + (size_t)b * LL;
    for (int t = tid; t < LL; t += NTH)
        outb[t] = (t < lenb) ? (int)sm.tags[t] : 0;
}

extern "C" void kernel_launch(void* const* d_in, const int* in_sizes, int n_in,
                              void* d_out, int out_size, void* d_ws, size_t ws_size,
                              hipStream_t stream) {
    const float* x       = (const float*)d_in[0];
    const int*   lengths = (const int*)d_in[1];
    // d_in[2] = tags (unused by decode)
    const float* trans   = (const float*)d_in[3];
    int*         out     = (int*)d_out;

    // Backpointers entirely in LDS: 128 KB dynamic + ~5.6 KB static < 160 KB.
    const int dyn = LL * TT;  // 131072 bytes
    hipFuncSetAttribute((const void*)&viterbi_kernel,
                        hipFuncAttributeMaxDynamicSharedMemorySize, dyn);
    viterbi_kernel<<<BB, NTH, dyn, stream>>>(x, lengths, trans, out);
}